// Round 9
// baseline (186.939 us; speedup 1.0000x reference)
//
#include <hip/hip_runtime.h>

// Blockwise 16x16 2D DCT (out = K @ T @ K^T), fp32, memory-bound.
// R8: 2048 blocks x 128 thr (2 waves) on 16x128 strips -> 8 blocks/CU,
// 16 waves/CU as 8 independent pipelines. Register prefetch 2 strips deep
// (2-iter load slack, 2-iter store slack), fast symmetric DCT, 2 light
// (2-wave) barriers/iter. All LDS b128 accesses bank-balanced (8 dw/bank).

#define IMG_W  1024
#define SCOLS  128
#define U0     2048         // U region after ibuf (16x128)
#define UTILE  336          // per-tile: 16*20 + 16 slack (keeps tile bases rotating)
#define USTR   20           // 80B rows: 16B-aligned
#define LDS_FLOATS 4736     // 2048 + 8*336 = 18944 B -> 8 blocks/CU

typedef float floatx4 __attribute__((ext_vector_type(4)));

// u[i] = sum_j K[i][j]*t[j] via even/odd symmetry of the DCT-II matrix:
// 96 fma + 24 add, kern reads are contiguous row prefixes.
__device__ __forceinline__ void dct16_fast(const float t[16],
                                           const float* __restrict__ kern,
                                           float u[16]) {
    float s[8], d[8];
    #pragma unroll
    for (int n = 0; n < 8; ++n) { s[n] = t[n] + t[15 - n]; d[n] = t[n] - t[15 - n]; }
    float ss[4], sd[4];
    #pragma unroll
    for (int n = 0; n < 4; ++n) { ss[n] = s[n] + s[7 - n]; sd[n] = s[n] - s[7 - n]; }
    #pragma unroll
    for (int k = 0; k < 4; ++k) {
        float a = 0.0f, b = 0.0f;
        #pragma unroll
        for (int n = 0; n < 4; ++n) {
            a = fmaf(kern[(4 * k) * 16 + n],     ss[n], a);
            b = fmaf(kern[(4 * k + 2) * 16 + n], sd[n], b);
        }
        u[4 * k] = a; u[4 * k + 2] = b;
    }
    #pragma unroll
    for (int k = 0; k < 8; ++k) {
        float a = 0.0f;
        #pragma unroll
        for (int n = 0; n < 8; ++n)
            a = fmaf(kern[(2 * k + 1) * 16 + n], d[n], a);
        u[2 * k + 1] = a;
    }
}

__global__ __launch_bounds__(128, 4) void dct16_kernel(
    const float* __restrict__ x,
    const float* __restrict__ kern,      // 16x16 DCT matrix, row-major
    float* __restrict__ out,
    int strips_per_block, int total_strips)
{
    __shared__ float lds[LDS_FLOATS];

    const int tid  = threadIdx.x;        // 0..127
    const int lane = tid & 63;
    const int wid  = tid >> 6;           // 0..1

    int s0 = blockIdx.x * strips_per_block;
    if (s0 >= total_strips) return;      // uniform per block
    int ns = strips_per_block;
    if (s0 + ns > total_strips) ns = total_strips - s0;

    // strip s: 16 rows x 128 cols. band = s>>3, eighth = s&7.
    auto sbase = [](int s) -> size_t {
        return (size_t)(s >> 3) * (16 * IMG_W) + (size_t)(s & 7) * SCOLS;
    };

    // per-instr f: rows 8*wid + 2*f + (lane>>5), col (lane&31)*4 -> 512B runs
    const int g_row = 8 * wid + (lane >> 5);     // +2*f
    const int g_col = (lane & 31) * 4;

    floatx4 preA[4], preB[4];            // 2-deep strip prefetch (32 VGPRs)

    auto load_strip = [&](int s, floatx4* pre) {
        const float* g = x + sbase(s) + (size_t)g_row * IMG_W + g_col;
        #pragma unroll
        for (int f = 0; f < 4; ++f)
            pre[f] = *reinterpret_cast<const floatx4*>(g + (size_t)(2 * f) * IMG_W);
    };
    auto write_strip = [&](const floatx4* pre) {   // regs -> ibuf (vmcnt auto)
        #pragma unroll
        for (int f = 0; f < 4; ++f)
            *reinterpret_cast<floatx4*>(&lds[(g_row + 2 * f) * SCOLS + g_col]) = pre[f];
    };

    // prologue: strip s0 -> ibuf; s0+1 in A, s0+2 in B (in flight)
    load_strip(s0, preA);
    write_strip(preA);
    if (ns > 1) load_strip(s0 + 1, preA);
    if (ns > 2) load_strip(s0 + 2, preB);

    for (int k = 0; k < ns; ++k) {
        asm volatile("s_waitcnt lgkmcnt(0)" ::: "memory");
        __builtin_amdgcn_s_barrier();    // B_top: ibuf = strip k (2-wave)
        asm volatile("" ::: "memory");

        // ---- Pass 1: U = K @ T. Thread = column c = tid (128 cols). ----
        {
            const int t  = tid >> 4;     // tile 0..7
            const int cl = tid & 15;
            float tv[16];
            #pragma unroll
            for (int j = 0; j < 16; ++j) tv[j] = lds[j * SCOLS + tid];

            float u[16];
            dct16_fast(tv, kern, u);

            float* U = &lds[U0 + t * UTILE];
            #pragma unroll
            for (int i = 0; i < 16; ++i)
                U[i * USTR + cl] = u[i];
        }

        // ---- Pass 2: O = U @ K^T. Thread = (tile, row). Wave-local. ----
        {
            const int t = tid >> 4;
            const int r = tid & 15;
            float* Ur = &lds[U0 + t * UTILE + r * USTR];

            float ur[16];
            #pragma unroll
            for (int p = 0; p < 4; ++p) {
                floatx4 v = *reinterpret_cast<const floatx4*>(Ur + p * 4);
                ur[p*4+0] = v.x; ur[p*4+1] = v.y; ur[p*4+2] = v.z; ur[p*4+3] = v.w;
            }

            float o[16];
            dct16_fast(ur, kern, o);

            #pragma unroll
            for (int f = 0; f < 4; ++f) {
                floatx4 v = { o[f*4+0], o[f*4+1], o[f*4+2], o[f*4+3] };
                *reinterpret_cast<floatx4*>(Ur + f * 4) = v;
            }
        }
        asm volatile("s_waitcnt lgkmcnt(0)" ::: "memory");
        __builtin_amdgcn_s_barrier();    // B_mid: all tiles final (2-wave)
        asm volatile("" ::: "memory");

        // ---- Tail: stage-read, ds_write k+1, issue loads k+3, store k ----
        {
            // out[row][col] = U[col>>4 tile][row][col&15]
            const int t  = (lane & 31) >> 2;
            const int c0 = ((lane & 31) & 3) * 4;
            floatx4 sv[4];
            #pragma unroll
            for (int f = 0; f < 4; ++f)
                sv[f] = *reinterpret_cast<const floatx4*>(
                    &lds[U0 + t * UTILE + (g_row + 2 * f) * USTR + c0]);

            floatx4* buf = (k & 1) ? preB : preA;
            if (k + 1 < ns) write_strip(buf);            // strip k+1 -> ibuf
            if (k + 3 < ns) load_strip(s0 + k + 3, buf); // refill, 2-iter slack

            float* g = out + sbase(s0 + k) + (size_t)g_row * IMG_W + g_col;
            #pragma unroll
            for (int f = 0; f < 4; ++f)
                *reinterpret_cast<floatx4*>(g + (size_t)(2 * f) * IMG_W) = sv[f];
        }
    }
}

extern "C" void kernel_launch(void* const* d_in, const int* in_sizes, int n_in,
                              void* d_out, int out_size, void* d_ws, size_t ws_size,
                              hipStream_t stream) {
    const float* x    = (const float*)d_in[0];
    const float* kern = (const float*)d_in[1];
    float* out        = (float*)d_out;

    const int n_img        = in_sizes[0] / (IMG_W * IMG_W);   // 96
    const int total_strips = n_img * 64 * 8;                  // 49152 strips of 16x128
    const int blocks       = 2048;                            // 8 per CU
    const int per_block    = (total_strips + blocks - 1) / blocks;  // 24, exact

    dct16_kernel<<<blocks, 128, 0, stream>>>(x, kern, out, per_block, total_strips);
}